// Round 1
// baseline (83.376 us; speedup 1.0000x reference)
//
#include <hip/hip_runtime.h>

// Patlak/extended-Tofts signal model, fully pointwise over (b, h, w) with a
// sequential t-loop carrying the Cp cumsum in a register.
//
// St[b,t,p] = (1 - e) * (1 - cosFA*expP) * S0 / ((1 - cosFA*e)*(1 - expP) + EPS)
//   where P = TR/(T1+EPS), expP = exp(-P),
//         Ct = vp*Cp[t] + Ktrans*DELTT*cumsum(Cp)[t],
//         e  = exp(-P - R1*(TR/1000)*Ct)
//
// Hoisted per-pixel:  A = (1-cosFA*expP)*S0,  B = (1-expP)+EPS,  C = cosFA*(1-expP)
// Inner loop:         e = __expf(-P - 0.0225f*Ct);  St = (A - A*e) * rcp(B - C*e)

#define HW_   (256 * 256)
#define NT_   60

__global__ __launch_bounds__(256) void patlak_kernel(
    const float* __restrict__ params,   // (B, 2, H, W)
    const float* __restrict__ Cp,       // (B, T)
    const float* __restrict__ S0,       // (B, 1, H, W)
    const float* __restrict__ T1,       // (B, 1, H, W)
    float* __restrict__ out)            // (B, T, H, W)
{
    __shared__ float s_cp[NT_];

    const int gid = blockIdx.x * 256 + threadIdx.x;  // 0 .. B*HW-1
    const int b   = gid >> 16;                       // HW = 65536
    const int p   = gid & (HW_ - 1);

    // Stage this batch's Cp row into LDS (block never straddles batches:
    // HW % 256 == 0).
    if (threadIdx.x < NT_) s_cp[threadIdx.x] = Cp[b * NT_ + threadIdx.x];
    __syncthreads();

    const float pk = params[(b * 2 + 0) * HW_ + p];  // Ktrans raw
    const float vp = params[(b * 2 + 1) * HW_ + p];
    const float s0 = S0[b * HW_ + p];
    const float t1 = T1[b * HW_ + p];

    const float ktD   = pk * (4.0f / 60.0f);         // Ktrans/60 * DELTT
    const float P     = 5.0f / (t1 + 1e-8f);         // TR/(T1+EPS)
    const float expP  = __expf(-P);
    const float cosfa = 0.9848077530122080594f;      // cos(10 deg)
    const float A     = (1.0f - cosfa * expP) * s0;
    const float omp   = 1.0f - expP;
    const float B     = omp + 1e-8f;
    const float C     = cosfa * omp;

    float ce = 0.0f;                                 // running cumsum(Cp)
    float* outp = out + (size_t)b * NT_ * HW_ + p;

    #pragma unroll 4
    for (int t = 0; t < NT_; ++t) {
        const float cp = s_cp[t];
        ce += cp;
        const float Ct  = vp * cp + ktD * ce;        // tissue concentration
        const float e   = __expf(-P - 0.0225f * Ct); // exp(-P - R1*TR/1000*Ct)
        const float num = A - A * e;
        const float den = B - C * e;
        outp[(size_t)t * HW_] = num * __builtin_amdgcn_rcpf(den);
    }
}

extern "C" void kernel_launch(void* const* d_in, const int* in_sizes, int n_in,
                              void* d_out, int out_size, void* d_ws, size_t ws_size,
                              hipStream_t stream) {
    const float* params = (const float*)d_in[0];
    const float* Cp     = (const float*)d_in[1];
    const float* S0     = (const float*)d_in[2];
    const float* T1     = (const float*)d_in[3];
    float* out          = (float*)d_out;

    const int total  = 4 * HW_;          // B * H * W pixels
    const int blocks = total / 256;      // 1024
    patlak_kernel<<<blocks, 256, 0, stream>>>(params, Cp, S0, T1, out);
}

// Round 2
// 82.011 us; speedup vs baseline: 1.0166x; 1.0166x over previous
//
#include <hip/hip_runtime.h>

// Patlak/extended-Tofts signal model.
// Round-2 structure: 4 pixels/thread (float4 in/out), t-loop split into 4
// chunks of 15 so grid = 1024 blocks (4 waves/SIMD). Cp prefix-sum is
// computed once per block via a wave shfl-scan, making all t independent.
//
// St = (A - A*e) / (B - C*e),  e = exp(-P - 0.0225*Ct),
// Ct = vp*Cp[t] + (Ktrans*DELTT/60)*cumsum(Cp)[t]
// A = (1-cosFA*exp(-P))*S0, B = (1-exp(-P))+EPS, C = cosFA*(1-exp(-P))

#define HW_   (256 * 256)
#define NT_   60
#define TCH_  15          // t-chunk length (NT_/4)
#define PXT_  4           // pixels per thread

__global__ __launch_bounds__(256) void patlak_kernel(
    const float* __restrict__ params,   // (B, 2, H, W)
    const float* __restrict__ Cp,       // (B, T)
    const float* __restrict__ S0,       // (B, 1, H, W)
    const float* __restrict__ T1,       // (B, 1, H, W)
    float* __restrict__ out)            // (B, T, H, W)
{
    __shared__ float s_cp[NT_];
    __shared__ float s_ce[NT_];   // inclusive cumsum of Cp (raw, DELTT folded later)

    const int bid = blockIdx.x;       // 0..1023
    const int b   = bid >> 8;         // 4 batches
    const int rem = bid & 255;
    const int c   = rem >> 6;         // t-chunk 0..3
    const int blk = rem & 63;         // pixel-block within image
    const int tid = threadIdx.x;

    // --- Cp row + prefix sum, once per block (wave-0 shfl inclusive scan) ---
    if (tid < 64) {
        float v = (tid < NT_) ? Cp[b * NT_ + tid] : 0.0f;
        float s = v;
        #pragma unroll
        for (int d = 1; d < 64; d <<= 1) {
            float u = __shfl_up(s, d, 64);
            if (tid >= d) s += u;
        }
        if (tid < NT_) { s_cp[tid] = v; s_ce[tid] = s; }
    }
    __syncthreads();

    const int p4 = (blk * 256 + tid) * PXT_;   // first of 4 consecutive pixels

    const float4 kt4 = *(const float4*)(params + (size_t)(b * 2 + 0) * HW_ + p4);
    const float4 vp4 = *(const float4*)(params + (size_t)(b * 2 + 1) * HW_ + p4);
    const float4 s04 = *(const float4*)(S0 + (size_t)b * HW_ + p4);
    const float4 t14 = *(const float4*)(T1 + (size_t)b * HW_ + p4);

    const float cosfa = 0.9848077530122080594f;  // cos(10 deg)

    float kD[PXT_], vp[PXT_], P[PXT_], A[PXT_], Bv[PXT_], Cv[PXT_];
    {
        const float kt_[4] = {kt4.x, kt4.y, kt4.z, kt4.w};
        const float vp_[4] = {vp4.x, vp4.y, vp4.z, vp4.w};
        const float s0_[4] = {s04.x, s04.y, s04.z, s04.w};
        const float t1_[4] = {t14.x, t14.y, t14.z, t14.w};
        #pragma unroll
        for (int i = 0; i < PXT_; ++i) {
            kD[i] = kt_[i] * (4.0f / 60.0f);        // Ktrans/60 * DELTT
            vp[i] = vp_[i];
            P[i]  = 5.0f / (t1_[i] + 1e-8f);        // TR/(T1+EPS)
            const float ep  = __expf(-P[i]);
            const float omp = 1.0f - ep;
            A[i]  = (1.0f - cosfa * ep) * s0_[i];
            Bv[i] = omp + 1e-8f;
            Cv[i] = cosfa * omp;
        }
    }

    const int t0 = c * TCH_;
    float* outp = out + ((size_t)b * NT_ + t0) * HW_ + p4;

    #pragma unroll 5
    for (int i = 0; i < TCH_; ++i) {
        const float cp = s_cp[t0 + i];
        const float ce = s_ce[t0 + i];
        float4 r;
        float res[PXT_];
        #pragma unroll
        for (int j = 0; j < PXT_; ++j) {
            const float Ct = vp[j] * cp + kD[j] * ce;
            const float e  = __expf(-P[j] - 0.0225f * Ct);  // R1*TR/1000 = 0.0225
            const float num = A[j] - A[j] * e;
            const float den = Bv[j] - Cv[j] * e;
            res[j] = num * __builtin_amdgcn_rcpf(den);
        }
        r.x = res[0]; r.y = res[1]; r.z = res[2]; r.w = res[3];
        *(float4*)outp = r;
        outp += HW_;
    }
}

extern "C" void kernel_launch(void* const* d_in, const int* in_sizes, int n_in,
                              void* d_out, int out_size, void* d_ws, size_t ws_size,
                              hipStream_t stream) {
    const float* params = (const float*)d_in[0];
    const float* Cp     = (const float*)d_in[1];
    const float* S0     = (const float*)d_in[2];
    const float* T1     = (const float*)d_in[3];
    float* out          = (float*)d_out;

    // 4 batches * 4 t-chunks * 64 pixel-blocks = 1024 blocks of 256 threads;
    // each thread: 4 pixels * 15 timepoints.
    patlak_kernel<<<1024, 256, 0, stream>>>(params, Cp, S0, T1, out);
}